// Round 7
// baseline (11006.952 us; speedup 1.0000x reference)
//
#include <hip/hip_runtime.h>
#include <math.h>

// ESN reservoir: B=1, T=2048, I=8, R=4096, O=8.
// h_t = tanh(Win x_t + W h_{t-1}); y_t = Wout h_t + b.
//
// R7 = R6 (flagless tag-in-data 8B packets, per-launch epoch tag, relaxed
// SYSTEM-scope write-through producer stores) with the exchange read path
// restructured:
//  - round 0: NORMAL CACHED loads (wg-scope relaxed atomic -> plain
//    global_load_dwordx2). The 32 WGs of an XCD coalesce in L2 MSHRs ->
//    L3 sees ~256 KB/step instead of 8 MB/round (R6's congestion collapse;
//    41 ms outlier dispatches).
//  - retry: only stale rows, predicated, SYSTEM-scope (L2-bypass) loads --
//    immune to stale lines cached by round 0, no deadlock, no full re-read.
// Compute & reduction order bit-identical to R4/R5/R6 (absmax 0.0078125).

#define T_STEPS 2048
#define R_DIM   4096
#define I_DIM   8
#define O_DIM   8
#define NWG     256
#define ROWS_PER_WG (R_DIM / NWG)   // 16
#define POOL_CAP 8192               // mean nnz/WG = 6554, ~21 sigma headroom
#define BLOCK    256
#define TAG_MUL  4096

__device__ unsigned long long g_pack[(size_t)T_STEPS * R_DIM];  // 64 MB
__device__ unsigned int      g_epoch;

__global__ void esn_init_kernel() {
    if (threadIdx.x == 0) {
        unsigned e = __hip_atomic_load(&g_epoch, __ATOMIC_RELAXED,
                                       __HIP_MEMORY_SCOPE_SYSTEM) + 1u;
        __hip_atomic_store(&g_epoch, e, __ATOMIC_RELAXED,
                           __HIP_MEMORY_SCOPE_SYSTEM);
    }
}

__launch_bounds__(BLOCK, 1)
__global__ void esn_recur_kernel(const float* __restrict__ x,
                                 const float* __restrict__ Win,
                                 const float* __restrict__ W) {
    __shared__ uint2 s_pool[POOL_CAP];                // 64 KB (val bits, idx)
    __shared__ float s_h[R_DIM];                      // 16 KB
    __shared__ int   s_start[ROWS_PER_WG + 1];
    __shared__ int   s_cnt[ROWS_PER_WG];
    __shared__ float s_win[ROWS_PER_WG][I_DIM];

    const int wg   = blockIdx.x;
    const int tid  = threadIdx.x;
    const int lane = tid & 63;
    const int wave = tid >> 6;
    const int row0 = wg * ROWS_PER_WG;

    const unsigned tag_base =
        __hip_atomic_load(&g_epoch, __ATOMIC_RELAXED,
                          __HIP_MEMORY_SCOPE_SYSTEM) * TAG_MUL;

    // ---------- one-time setup: compact 16 rows of W into LDS (order as R4) ----------
    for (int rr = wave; rr < ROWS_PER_WG; rr += 4) {
        const float* wrow = W + (size_t)(row0 + rr) * R_DIM;
        int cnt = 0;
        for (int base = 0; base < R_DIM; base += 64) {
            float v = wrow[base + lane];
            cnt += __popcll(__ballot(v != 0.0f));
        }
        if (lane == 0) s_cnt[rr] = cnt;
    }
    __syncthreads();
    if (tid == 0) {
        int acc = 0;
        for (int rr = 0; rr < ROWS_PER_WG; ++rr) {
            s_start[rr] = (acc < POOL_CAP) ? acc : POOL_CAP;
            acc += s_cnt[rr];
        }
        s_start[ROWS_PER_WG] = (acc < POOL_CAP) ? acc : POOL_CAP;
    }
    __syncthreads();
    for (int rr = wave; rr < ROWS_PER_WG; rr += 4) {
        const float* wrow = W + (size_t)(row0 + rr) * R_DIM;
        int off = s_start[rr];
        for (int base = 0; base < R_DIM; base += 64) {
            float v = wrow[base + lane];
            unsigned long long m = __ballot(v != 0.0f);
            int pre = __popcll(m & ((1ull << lane) - 1ull));
            if (v != 0.0f) {
                int pos = off + pre;
                if (pos < POOL_CAP) {
                    s_pool[pos].x = __float_as_uint(v);
                    s_pool[pos].y = base + lane;
                }
            }
            off += __popcll(m);
        }
    }
    if (tid < ROWS_PER_WG * I_DIM) {
        int rr = tid / I_DIM, c = tid % I_DIM;
        s_win[rr][c] = Win[(size_t)(row0 + rr) * I_DIM + c];
    }
    __syncthreads();

    const int row16 = tid >> 4;          // 0..15: which of my 16 rows
    const int sub   = tid & 15;          // 16 threads per row (as R4)
    const int start = s_start[row16];
    const int cnt   = s_start[row16 + 1] - start;

    // ---------- time loop ----------
    for (int t = 0; t < T_STEPS; ++t) {
        if (t > 0) {
            const unsigned exp_tag = tag_base + (unsigned)t;  // packets for t-1 carry tag_base+t
            __syncthreads();   // previous step's s_h readers done

            const unsigned long long* hp =
                g_pack + (size_t)(t - 1) * R_DIM + tid;
            unsigned long long u[16];
            // round 0: cached loads (L2-amortized across the XCD's 32 WGs)
            #pragma unroll
            for (int k = 0; k < 16; ++k)
                u[k] = __hip_atomic_load(hp + (k << 8), __ATOMIC_RELAXED,
                                         __HIP_MEMORY_SCOPE_WORKGROUP);
            // retry only stale rows with L2-bypass loads (fresh from L3)
            for (;;) {
                bool ok = true;
                #pragma unroll
                for (int k = 0; k < 16; ++k)
                    ok &= ((unsigned)(u[k] >> 32) == exp_tag);
                if (__all(ok)) break;
                #pragma unroll
                for (int k = 0; k < 16; ++k)
                    if ((unsigned)(u[k] >> 32) != exp_tag)
                        u[k] = __hip_atomic_load(hp + (k << 8), __ATOMIC_RELAXED,
                                                 __HIP_MEMORY_SCOPE_SYSTEM);
            }
            #pragma unroll
            for (int k = 0; k < 16; ++k)
                s_h[tid + (k << 8)] = __uint_as_float((unsigned)u[k]);
            __syncthreads();
        }

        // sparse row-dot: identical order to R4/R5/R6 (16-lane groups, stride 16)
        float acc = 0.0f;
        if (t > 0) {
            for (int e = start + sub; e < start + cnt; e += 16) {
                uint2 p = s_pool[e];
                acc += __uint_as_float(p.x) * s_h[p.y];
            }
        }
        acc += __shfl_xor(acc, 8, 16);
        acc += __shfl_xor(acc, 4, 16);
        acc += __shfl_xor(acc, 2, 16);
        acc += __shfl_xor(acc, 1, 16);

        if (sub == 0) {
            const float* xt = x + (size_t)t * I_DIM;
            float a = acc;
            #pragma unroll
            for (int c = 0; c < I_DIM; ++c) a += s_win[row16][c] * xt[c];
            float h = tanhf(a);
            unsigned long long pk =
                ((unsigned long long)(tag_base + (unsigned)(t + 1)) << 32) |
                (unsigned long long)__float_as_uint(h);
            __hip_atomic_store(&g_pack[(size_t)t * R_DIM + row0 + row16], pk,
                               __ATOMIC_RELAXED, __HIP_MEMORY_SCOPE_SYSTEM);
        }
        // no tail barrier: next iteration's leading __syncthreads protects s_h
    }
}

// y_t = Wout h_t + b, one wave per timestep; accumulation order as R4/R5/R6.
__global__ void esn_out_kernel(const float* __restrict__ Wout_w,
                               const float* __restrict__ Wout_b,
                               float* __restrict__ out) {
    const int t = blockIdx.x;
    const int lane = threadIdx.x;  // 64 threads
    const unsigned long long* hp = g_pack + (size_t)t * R_DIM;
    float acc[O_DIM];
    #pragma unroll
    for (int o = 0; o < O_DIM; ++o) acc[o] = 0.0f;
    for (int i = lane; i < R_DIM; i += 256) {   // 16 iters, 4 indep loads each
        unsigned long long u0 = __hip_atomic_load(hp + i,       __ATOMIC_RELAXED, __HIP_MEMORY_SCOPE_SYSTEM);
        unsigned long long u1 = __hip_atomic_load(hp + i + 64,  __ATOMIC_RELAXED, __HIP_MEMORY_SCOPE_SYSTEM);
        unsigned long long u2 = __hip_atomic_load(hp + i + 128, __ATOMIC_RELAXED, __HIP_MEMORY_SCOPE_SYSTEM);
        unsigned long long u3 = __hip_atomic_load(hp + i + 192, __ATOMIC_RELAXED, __HIP_MEMORY_SCOPE_SYSTEM);
        float h0 = __uint_as_float((unsigned)u0);
        float h1 = __uint_as_float((unsigned)u1);
        float h2 = __uint_as_float((unsigned)u2);
        float h3 = __uint_as_float((unsigned)u3);
        #pragma unroll
        for (int o = 0; o < O_DIM; ++o) acc[o] += h0 * Wout_w[(size_t)o * R_DIM + i];
        #pragma unroll
        for (int o = 0; o < O_DIM; ++o) acc[o] += h1 * Wout_w[(size_t)o * R_DIM + i + 64];
        #pragma unroll
        for (int o = 0; o < O_DIM; ++o) acc[o] += h2 * Wout_w[(size_t)o * R_DIM + i + 128];
        #pragma unroll
        for (int o = 0; o < O_DIM; ++o) acc[o] += h3 * Wout_w[(size_t)o * R_DIM + i + 192];
    }
    #pragma unroll
    for (int o = 0; o < O_DIM; ++o) {
        float a = acc[o];
        a += __shfl_xor(a, 32);
        a += __shfl_xor(a, 16);
        a += __shfl_xor(a, 8);
        a += __shfl_xor(a, 4);
        a += __shfl_xor(a, 2);
        a += __shfl_xor(a, 1);
        if (lane == 0) out[(size_t)t * O_DIM + o] = a + Wout_b[o];
    }
}

extern "C" void kernel_launch(void* const* d_in, const int* in_sizes, int n_in,
                              void* d_out, int out_size, void* d_ws, size_t ws_size,
                              hipStream_t stream) {
    const float* x    = (const float*)d_in[0];   // [1,2048,8]
    const float* Win  = (const float*)d_in[1];   // [4096,8]
    const float* W    = (const float*)d_in[2];   // [4096,4096]
    const float* Ww   = (const float*)d_in[3];   // [8,4096]
    const float* Wb   = (const float*)d_in[4];   // [8]
    float* out = (float*)d_out;                  // [1,2048,8]

    hipLaunchKernelGGL(esn_init_kernel, dim3(1), dim3(64), 0, stream);

    void* args[] = { (void*)&x, (void*)&Win, (void*)&W };
    hipLaunchCooperativeKernel((void*)esn_recur_kernel, dim3(NWG), dim3(BLOCK),
                               args, 0, stream);

    hipLaunchKernelGGL(esn_out_kernel, dim3(T_STEPS), dim3(64), 0, stream,
                       Ww, Wb, out);
}